// Round 1
// baseline (166.717 us; speedup 1.0000x reference)
//
#include <hip/hip_runtime.h>

#define E_N 8192
#define V_N 2048
#define F_N 2048
#define B_N 8
#define H_N 128
#define DEC_N 128
#define EDGE_N 2
#define META_N 4
#define IN_DIM 134   // DEC + EDGE + META
#define MEMH 256
#define MEMAGG 128
#define AGGH 128

// ---------------------------------------------------------------------------
// batch_of_var[v] = argmax_b b_variable_mask[v][b]  (exactly one 1 per row)
__global__ void k_bov(const float* __restrict__ bvm, int* __restrict__ bov) {
    int v = blockIdx.x * blockDim.x + threadIdx.x;
    if (v < V_N) {
        float s = 0.f;
#pragma unroll
        for (int b = 0; b < B_N; ++b) s += bvm[v * B_N + b] * (float)b;
        bov[v] = (int)(s + 0.5f);
    }
}

// ---------------------------------------------------------------------------
// Recover var_idx / fun_idx from the dense one-hot rows of the transposed
// incidence matrices: idx[e] = row_e . iota  (one wave per edge, float4 reads).
__global__ __launch_bounds__(256) void k_idx(const float* __restrict__ vmt,
                                             const float* __restrict__ fmt,
                                             int* __restrict__ vidx,
                                             int* __restrict__ fidx) {
    int wave = (int)((blockIdx.x * blockDim.x + threadIdx.x) >> 6);
    int lane = threadIdx.x & 63;
    const float* m;
    int* out;
    int e;
    if (wave < E_N) { m = vmt; out = vidx; e = wave; }
    else            { m = fmt; out = fidx; e = wave - E_N; }
    const float4* row = (const float4*)(m + (size_t)e * V_N);
    float partial = 0.f;
#pragma unroll
    for (int c4 = lane; c4 < V_N / 4; c4 += 64) {
        float4 v = row[c4];
        int c = c4 * 4;
        partial += v.x * (float)c + v.y * (float)(c + 1) +
                   v.z * (float)(c + 2) + v.w * (float)(c + 3);
    }
#pragma unroll
    for (int off = 32; off > 0; off >>= 1) partial += __shfl_down(partial, off);
    if (lane == 0) out[e] = (int)(partial + 0.5f);
}

// ---------------------------------------------------------------------------
// Per-edge broadcast quantities: edge mask (active flag) and graph features.
__global__ void k_meta(const int* __restrict__ vidx, const int* __restrict__ bov,
                       const int* __restrict__ active, const float* __restrict__ meta,
                       float* __restrict__ emask, float* __restrict__ gfeat) {
    int e = blockIdx.x * blockDim.x + threadIdx.x;
    if (e < E_N) {
        int b = bov[vidx[e]];
        emask[e] = (float)active[b];
        ((float4*)gfeat)[e] = ((const float4*)meta)[b];
    }
}

// ---------------------------------------------------------------------------
// MLP1 (134->256, relu) + MLP2 (256->128) per edge, tile of 16 edges/block.
// Also scatter-adds h2 into the per-node sums (atomics).
__global__ __launch_bounds__(256) void k_mlp(
    const float* __restrict__ dec,   // (E,128)
    const float* __restrict__ ef,    // (E,2)
    const float* __restrict__ gfeat, // (E,4)
    const float* __restrict__ W1, const float* __restrict__ b1,  // (134,256),(256)
    const float* __restrict__ W2, const float* __restrict__ b2,  // (256,128),(128)
    const int* __restrict__ idx,
    float* __restrict__ h2out,    // (E,128)
    float* __restrict__ nodesum)  // (V,128)
{
    __shared__ float dvs[16][IN_DIM];
    __shared__ float h1[16][MEMH];
    int t = threadIdx.x;
    int e0 = blockIdx.x * 16;

    for (int i = t; i < 16 * IN_DIM; i += 256) {
        int e = i / IN_DIM, k = i % IN_DIM;
        float val;
        if (k < DEC_N)               val = dec[(size_t)(e0 + e) * DEC_N + k];
        else if (k < DEC_N + EDGE_N) val = ef[(e0 + e) * EDGE_N + (k - DEC_N)];
        else                         val = gfeat[(e0 + e) * META_N + (k - DEC_N - EDGE_N)];
        dvs[e][k] = val;
    }
    __syncthreads();

    {   // h1: thread t owns output column c=t for all 16 edges
        int c = t;
        float acc[16];
#pragma unroll
        for (int e = 0; e < 16; ++e) acc[e] = b1[c];
        for (int k = 0; k < IN_DIM; ++k) {
            float w = W1[k * MEMH + c];
#pragma unroll
            for (int e = 0; e < 16; ++e) acc[e] += dvs[e][k] * w;
        }
#pragma unroll
        for (int e = 0; e < 16; ++e) h1[e][c] = fmaxf(acc[e], 0.f);
    }
    __syncthreads();

    {   // h2: thread t owns column c=t&127 for 8 edges
        int c = t & 127;
        int eb = (t >> 7) * 8;
        float acc[8];
#pragma unroll
        for (int e = 0; e < 8; ++e) acc[e] = b2[c];
        for (int k = 0; k < MEMH; ++k) {
            float w = W2[k * MEMAGG + c];
#pragma unroll
            for (int e = 0; e < 8; ++e) acc[e] += h1[eb + e][k] * w;
        }
#pragma unroll
        for (int e = 0; e < 8; ++e) {
            int ge = e0 + eb + e;
            h2out[(size_t)ge * MEMAGG + c] = acc[e];
            atomicAdd(&nodesum[(size_t)idx[ge] * MEMAGG + c], acc[e]);
        }
    }
}

// ---------------------------------------------------------------------------
// agg = nodesum[idx[e]] - h2[e]; a = relu([agg,ef]@A1+c1); o = a@A2+c2;
// out = m*o + (1-m)*old_state
__global__ __launch_bounds__(256) void k_post(
    const float* __restrict__ h2,      // (E,128)
    const float* __restrict__ nodesum, // (V,128)
    const float* __restrict__ ef,      // (E,2)
    const float* __restrict__ A1, const float* __restrict__ c1,  // (130,128)
    const float* __restrict__ A2, const float* __restrict__ c2,  // (128,128)
    const int* __restrict__ idx,
    const float* __restrict__ emask,
    const float* __restrict__ oldstate, // (E,128)
    float* __restrict__ outstate)       // (E,128)
{
    __shared__ float inb[16][MEMAGG + EDGE_N];  // 130
    __shared__ float a[16][AGGH];
    int t = threadIdx.x;
    int e0 = blockIdx.x * 16;

    for (int i = t; i < 16 * MEMAGG; i += 256) {
        int e = i >> 7, k = i & 127;
        int ge = e0 + e;
        inb[e][k] = nodesum[(size_t)idx[ge] * MEMAGG + k] - h2[(size_t)ge * MEMAGG + k];
    }
    if (t < 32) {
        int e = t >> 1, j = t & 1;
        inb[e][MEMAGG + j] = ef[(e0 + e) * EDGE_N + j];
    }
    __syncthreads();

    {   // a = relu(in @ A1 + c1)
        int c = t & 127, eb = (t >> 7) * 8;
        float acc[8];
#pragma unroll
        for (int e = 0; e < 8; ++e) acc[e] = c1[c];
        for (int k = 0; k < MEMAGG + EDGE_N; ++k) {
            float w = A1[k * AGGH + c];
#pragma unroll
            for (int e = 0; e < 8; ++e) acc[e] += inb[eb + e][k] * w;
        }
#pragma unroll
        for (int e = 0; e < 8; ++e) a[eb + e][c] = fmaxf(acc[e], 0.f);
    }
    __syncthreads();

    {   // o = a @ A2 + c2, then mask-blend with old state
        int c = t & 127, eb = (t >> 7) * 8;
        float acc[8];
#pragma unroll
        for (int e = 0; e < 8; ++e) acc[e] = c2[c];
        for (int k = 0; k < AGGH; ++k) {
            float w = A2[k * H_N + c];
#pragma unroll
            for (int e = 0; e < 8; ++e) acc[e] += a[eb + e][k] * w;
        }
#pragma unroll
        for (int e = 0; e < 8; ++e) {
            int ge = e0 + eb + e;
            float m = emask[ge];
            outstate[(size_t)ge * H_N + c] =
                m * acc[e] + (1.f - m) * oldstate[(size_t)ge * H_N + c];
        }
    }
}

// ---------------------------------------------------------------------------
extern "C" void kernel_launch(void* const* d_in, const int* in_sizes, int n_in,
                              void* d_out, int out_size, void* d_ws, size_t ws_size,
                              hipStream_t stream) {
    const float* variable_state = (const float*)d_in[0];
    const float* function_state = (const float*)d_in[1];
    const float* dec_v          = (const float*)d_in[2];
    const float* dec_f          = (const float*)d_in[3];
    const float* ef             = (const float*)d_in[4];
    const float* meta           = (const float*)d_in[5];
    const int*   active         = (const int*)d_in[6];
    // d_in[7] variable_mask (unused), d_in[9] function_mask (unused)
    const float* vmask_t        = (const float*)d_in[8];
    const float* fmask_t        = (const float*)d_in[10];
    const float* bvm            = (const float*)d_in[11];
    const float* vM1w = (const float*)d_in[12]; const float* vM1b = (const float*)d_in[13];
    const float* vM2w = (const float*)d_in[14]; const float* vM2b = (const float*)d_in[15];
    const float* vA1w = (const float*)d_in[16]; const float* vA1b = (const float*)d_in[17];
    const float* vA2w = (const float*)d_in[18]; const float* vA2b = (const float*)d_in[19];
    const float* fM1w = (const float*)d_in[20]; const float* fM1b = (const float*)d_in[21];
    const float* fM2w = (const float*)d_in[22]; const float* fM2b = (const float*)d_in[23];
    const float* fA1w = (const float*)d_in[24]; const float* fA1b = (const float*)d_in[25];
    const float* fA2w = (const float*)d_in[26]; const float* fA2b = (const float*)d_in[27];

    float* out_vs = (float*)d_out;                        // new variable_state (E,H)
    float* out_fs = (float*)d_out + (size_t)E_N * H_N;    // new function_state (E,H)

    // workspace carve-up
    int*   var_idx = (int*)d_ws;                 // E
    int*   fun_idx = var_idx + E_N;              // E
    int*   bov     = fun_idx + E_N;              // V
    float* emask   = (float*)(bov + V_N);        // E
    float* gfeat   = emask + E_N;                // E*4
    float* hv2     = gfeat + (size_t)E_N * 4;    // E*128
    float* hf2     = hv2 + (size_t)E_N * MEMAGG; // E*128
    float* nsv     = hf2 + (size_t)E_N * MEMAGG; // V*128
    float* nsf     = nsv + (size_t)V_N * MEMAGG; // F*128

    hipMemsetAsync(nsv, 0, (size_t)(V_N + F_N) * MEMAGG * sizeof(float), stream);
    k_bov<<<(V_N + 255) / 256, 256, 0, stream>>>(bvm, bov);
    k_idx<<<(2 * E_N) / 4, 256, 0, stream>>>(vmask_t, fmask_t, var_idx, fun_idx);
    k_meta<<<E_N / 256, 256, 0, stream>>>(var_idx, bov, active, meta, emask, gfeat);

    // variable branch (produces new function_state)
    k_mlp<<<E_N / 16, 256, 0, stream>>>(dec_v, ef, gfeat, vM1w, vM1b, vM2w, vM2b,
                                        var_idx, hv2, nsv);
    // function branch (produces new variable_state)
    k_mlp<<<E_N / 16, 256, 0, stream>>>(dec_f, ef, gfeat, fM1w, fM1b, fM2w, fM2b,
                                        fun_idx, hf2, nsf);

    k_post<<<E_N / 16, 256, 0, stream>>>(hv2, nsv, ef, vA1w, vA1b, vA2w, vA2b,
                                         var_idx, emask, function_state, out_fs);
    k_post<<<E_N / 16, 256, 0, stream>>>(hf2, nsf, ef, fA1w, fA1b, fA2w, fA2b,
                                         fun_idx, emask, variable_state, out_vs);
}

// Round 2
// 68.674 us; speedup vs baseline: 2.4276x; 2.4276x over previous
//
#include <hip/hip_runtime.h>

#define E_N 8192
#define V_N 2048
#define F_N 2048
#define B_N 8
#define H_N 128
#define DEC_N 128
#define EDGE_N 2
#define META_N 4
#define IN_DIM 134
#define MEMH 256
#define MEMAGG 128
#define AGGH 128

typedef __attribute__((ext_vector_type(8))) short short8;
typedef __attribute__((ext_vector_type(4))) float f32x4;

__device__ inline unsigned short f2bf(float x) {
    unsigned u = __float_as_uint(x);
    unsigned r = (u + 0x7FFFu + ((u >> 16) & 1u)) >> 16;
    return (unsigned short)r;
}

__device__ inline short8 pack8(float4 u0, float4 u1) {
    short8 s;
    s[0] = (short)f2bf(u0.x); s[1] = (short)f2bf(u0.y);
    s[2] = (short)f2bf(u0.z); s[3] = (short)f2bf(u0.w);
    s[4] = (short)f2bf(u1.x); s[5] = (short)f2bf(u1.y);
    s[6] = (short)f2bf(u1.z); s[7] = (short)f2bf(u1.w);
    return s;
}

// ---------------------------------------------------------------------------
__global__ void k_bov(const float* __restrict__ bvm, int* __restrict__ bov) {
    int v = blockIdx.x * blockDim.x + threadIdx.x;
    if (v < V_N) {
        float s = 0.f;
#pragma unroll
        for (int b = 0; b < B_N; ++b) s += bvm[v * B_N + b] * (float)b;
        bov[v] = (int)(s + 0.5f);
    }
}

// ---------------------------------------------------------------------------
// One wave per row of the transposed incidence matrix; early-exit scan for
// the single 1 in each one-hot row (wave-uniform break via ballot).
__global__ __launch_bounds__(256) void k_idx(const float* __restrict__ vmt,
                                             const float* __restrict__ fmt,
                                             int* __restrict__ vidx,
                                             int* __restrict__ fidx) {
    int wave = (int)((blockIdx.x * blockDim.x + threadIdx.x) >> 6);
    int lane = threadIdx.x & 63;
    const float* m;
    int* out;
    int e;
    if (wave < E_N) { m = vmt; out = vidx; e = wave; }
    else            { m = fmt; out = fidx; e = wave - E_N; }
    const float4* row = (const float4*)(m + (size_t)e * V_N);
    for (int base = 0; base < V_N / 4; base += 64) {
        float4 v = row[base + lane];
        int hit = -1;
        int c = (base + lane) * 4;
        if      (v.x != 0.f) hit = c;
        else if (v.y != 0.f) hit = c + 1;
        else if (v.z != 0.f) hit = c + 2;
        else if (v.w != 0.f) hit = c + 3;
        unsigned long long bm = __ballot(hit >= 0);
        if (bm) {
            int src = __ffsll((long long)bm) - 1;
            int val = __shfl(hit, src);
            if (lane == 0) out[e] = val;
            break;
        }
    }
}

// ---------------------------------------------------------------------------
__global__ void k_meta(const int* __restrict__ vidx, const int* __restrict__ bov,
                       const int* __restrict__ active, const float* __restrict__ meta,
                       float* __restrict__ emask, float* __restrict__ gfeat) {
    int e = blockIdx.x * blockDim.x + threadIdx.x;
    if (e < E_N) {
        int b = bov[vidx[e]];
        emask[e] = (float)active[b];
        ((float4*)gfeat)[e] = ((const float4*)meta)[b];
    }
}

// ---------------------------------------------------------------------------
// Repack fp32 weights into MFMA B-fragment order, bf16, K padded to Kp with 0.
// Packed layout: frag f = kc*(N/16)+c16; element ((f*64)+lane)*8 + i holds
// B[32*kc + 8*(lane>>4) + i][16*c16 + (lane&15)].
struct RDesc { const float* src; unsigned short* dst; int K; int N; int Kp; };
struct RPack { RDesc d[8]; };

__global__ __launch_bounds__(256) void k_repack(RPack p) {
    RDesc d = p.d[blockIdx.y];
    int i = blockIdx.x * 256 + threadIdx.x;
    int total = d.Kp * d.N;
    if (i >= total) return;
    int elem = i & 7;
    int lane = (i >> 3) & 63;
    int f    = i >> 9;
    int c16n = d.N >> 4;
    int c16 = f % c16n, kc = f / c16n;
    int k = kc * 32 + (lane >> 4) * 8 + elem;
    int c = c16 * 16 + (lane & 15);
    float v = (k < d.K) ? d.src[(size_t)k * d.N + c] : 0.f;
    d.dst[i] = f2bf(v);
}

// ---------------------------------------------------------------------------
// Fused MLP1+MLP2 per edge via MFMA: h1 = relu(dvs@W1+b1); h2 = h1@W2+b2;
// h2 -> global + atomic scatter into per-node sums. Block = 32 edges, 4 waves.
struct F1Args {
    const float* dec[2];
    const float* ef;
    const float* gfeat;
    const unsigned short* wpack[2];  // W1f @0 (160x256), W2f @40960 (256x128)
    const float* b1[2];
    const float* b2[2];
    const int* idx[2];
    float* h2[2];
    float* ns[2];
};

__global__ __launch_bounds__(256) void k_fused1(F1Args A) {
    int br = blockIdx.y;
    const float* dec = A.dec[br];
    const unsigned short* W1f = A.wpack[br];
    const unsigned short* W2f = A.wpack[br] + 160 * 256;
    const float* b1 = A.b1[br];
    const float* b2 = A.b2[br];
    const int* idx = A.idx[br];
    float* h2o = A.h2[br];
    float* ns  = A.ns[br];

    int tid = threadIdx.x;
    int wave = tid >> 6, lane = tid & 63;
    int lrow = lane & 15, lgrp = lane >> 4;
    int e0 = blockIdx.x * 32;

    __shared__ unsigned short h1s[32 * 256];

    // ---- GEMM1: (32 x 256) = dvs(32 x 160pad) @ W1(160 x 256); wave owns 64 cols
    int n0 = wave * 64;
    f32x4 acc1[2][4];
#pragma unroll
    for (int nt = 0; nt < 4; ++nt) {
        float bv = b1[n0 + nt * 16 + lrow];
#pragma unroll
        for (int mt = 0; mt < 2; ++mt) acc1[mt][nt] = (f32x4){bv, bv, bv, bv};
    }
    const float4* dec4 = (const float4*)dec;
#pragma unroll
    for (int kc = 0; kc < 5; ++kc) {
        short8 a[2];
#pragma unroll
        for (int mt = 0; mt < 2; ++mt) {
            int r = e0 + mt * 16 + lrow;
            if (kc < 4) {
                float4 u0 = dec4[(size_t)r * 32 + kc * 8 + lgrp * 2];
                float4 u1 = dec4[(size_t)r * 32 + kc * 8 + lgrp * 2 + 1];
                a[mt] = pack8(u0, u1);
            } else {
                short8 z = (short8)0;
                if (lgrp == 0) {
                    z[0] = (short)f2bf(A.ef[r * 2]);
                    z[1] = (short)f2bf(A.ef[r * 2 + 1]);
                    z[2] = (short)f2bf(A.gfeat[r * 4]);
                    z[3] = (short)f2bf(A.gfeat[r * 4 + 1]);
                    z[4] = (short)f2bf(A.gfeat[r * 4 + 2]);
                    z[5] = (short)f2bf(A.gfeat[r * 4 + 3]);
                }
                a[mt] = z;
            }
        }
#pragma unroll
        for (int nt = 0; nt < 4; ++nt) {
            short8 b = *(const short8*)(W1f + ((size_t)(kc * 16 + (n0 >> 4) + nt) * 64 + lane) * 8);
#pragma unroll
            for (int mt = 0; mt < 2; ++mt)
                acc1[mt][nt] = __builtin_amdgcn_mfma_f32_16x16x32_bf16(a[mt], b, acc1[mt][nt], 0, 0, 0);
        }
    }
    // relu -> LDS (bf16, XOR-swizzled cols to kill bank conflicts)
#pragma unroll
    for (int mt = 0; mt < 2; ++mt)
#pragma unroll
        for (int nt = 0; nt < 4; ++nt)
#pragma unroll
            for (int j = 0; j < 4; ++j) {
                int row = mt * 16 + lgrp * 4 + j;
                int col = n0 + nt * 16 + lrow;
                h1s[row * 256 + (col ^ ((row & 7) << 3))] = f2bf(fmaxf(acc1[mt][nt][j], 0.f));
            }
    __syncthreads();

    // ---- GEMM2: (32 x 128) = h1(32 x 256) @ W2(256 x 128); wave owns 32 cols
    int c0 = wave * 32;
    f32x4 acc2[2][2];
#pragma unroll
    for (int nt = 0; nt < 2; ++nt) {
        float bv = b2[c0 + nt * 16 + lrow];
#pragma unroll
        for (int mt = 0; mt < 2; ++mt) acc2[mt][nt] = (f32x4){bv, bv, bv, bv};
    }
#pragma unroll
    for (int kc = 0; kc < 8; ++kc) {
        short8 a2[2];
#pragma unroll
        for (int mt = 0; mt < 2; ++mt) {
            int r = mt * 16 + lrow;
            int kb = kc * 32 + lgrp * 8;
            a2[mt] = *(const short8*)(h1s + r * 256 + (kb ^ ((r & 7) << 3)));
        }
#pragma unroll
        for (int nt = 0; nt < 2; ++nt) {
            short8 b = *(const short8*)(W2f + ((size_t)(kc * 8 + (c0 >> 4) + nt) * 64 + lane) * 8);
#pragma unroll
            for (int mt = 0; mt < 2; ++mt)
                acc2[mt][nt] = __builtin_amdgcn_mfma_f32_16x16x32_bf16(a2[mt], b, acc2[mt][nt], 0, 0, 0);
        }
    }
    // h2 -> global; scatter-add into node sums
#pragma unroll
    for (int mt = 0; mt < 2; ++mt)
#pragma unroll
        for (int nt = 0; nt < 2; ++nt) {
            int col = c0 + nt * 16 + lrow;
#pragma unroll
            for (int j = 0; j < 4; ++j) {
                int row = e0 + mt * 16 + lgrp * 4 + j;
                float v = acc2[mt][nt][j];
                h2o[(size_t)row * 128 + col] = v;
                atomicAdd(ns + (size_t)idx[row] * 128 + col, v);
            }
        }
}

// ---------------------------------------------------------------------------
// Fused post: agg = ns[idx]-h2; a = relu([agg,ef]@A1+c1); o = a@A2+c2;
// out = m*o + (1-m)*old.
struct F2Args {
    const unsigned short* wpack[2];  // A1f @73728 (160x128), A2f @94208 (128x128)
    const float* c1[2];
    const float* c2[2];
    const float* h2[2];
    const float* ns[2];
    const int* idx[2];
    const float* ef;
    const float* emask;
    const float* oldst[2];
    float* outst[2];
};

__global__ __launch_bounds__(256) void k_fused2(F2Args A) {
    int br = blockIdx.y;
    const unsigned short* A1f = A.wpack[br] + 160 * 256 + 256 * 128;
    const unsigned short* A2f = A1f + 160 * 128;
    const float* c1 = A.c1[br];
    const float* c2 = A.c2[br];
    const float* h2 = A.h2[br];
    const float* ns = A.ns[br];
    const int* idx = A.idx[br];
    const float* oldst = A.oldst[br];
    float* outst = A.outst[br];

    int tid = threadIdx.x;
    int wave = tid >> 6, lane = tid & 63;
    int lrow = lane & 15, lgrp = lane >> 4;
    int e0 = blockIdx.x * 32;

    __shared__ unsigned short as_[32 * 128];

    // ---- GEMM_p1: (32 x 128) = [agg|ef](32 x 160pad) @ A1(160 x 128)
    int n0 = wave * 32;
    f32x4 accp[2][2];
#pragma unroll
    for (int nt = 0; nt < 2; ++nt) {
        float bv = c1[n0 + nt * 16 + lrow];
#pragma unroll
        for (int mt = 0; mt < 2; ++mt) accp[mt][nt] = (f32x4){bv, bv, bv, bv};
    }
    const float4* ns4 = (const float4*)ns;
    const float4* h24 = (const float4*)h2;
#pragma unroll
    for (int kc = 0; kc < 5; ++kc) {
        short8 a[2];
#pragma unroll
        for (int mt = 0; mt < 2; ++mt) {
            int r = e0 + mt * 16 + lrow;
            if (kc < 4) {
                int node = idx[r];
                float4 u0 = ns4[(size_t)node * 32 + kc * 8 + lgrp * 2];
                float4 u1 = ns4[(size_t)node * 32 + kc * 8 + lgrp * 2 + 1];
                float4 v0 = h24[(size_t)r * 32 + kc * 8 + lgrp * 2];
                float4 v1 = h24[(size_t)r * 32 + kc * 8 + lgrp * 2 + 1];
                float4 d0 = {u0.x - v0.x, u0.y - v0.y, u0.z - v0.z, u0.w - v0.w};
                float4 d1 = {u1.x - v1.x, u1.y - v1.y, u1.z - v1.z, u1.w - v1.w};
                a[mt] = pack8(d0, d1);
            } else {
                short8 z = (short8)0;
                if (lgrp == 0) {
                    z[0] = (short)f2bf(A.ef[r * 2]);
                    z[1] = (short)f2bf(A.ef[r * 2 + 1]);
                }
                a[mt] = z;
            }
        }
#pragma unroll
        for (int nt = 0; nt < 2; ++nt) {
            short8 b = *(const short8*)(A1f + ((size_t)(kc * 8 + (n0 >> 4) + nt) * 64 + lane) * 8);
#pragma unroll
            for (int mt = 0; mt < 2; ++mt)
                accp[mt][nt] = __builtin_amdgcn_mfma_f32_16x16x32_bf16(a[mt], b, accp[mt][nt], 0, 0, 0);
        }
    }
    // relu -> LDS
#pragma unroll
    for (int mt = 0; mt < 2; ++mt)
#pragma unroll
        for (int nt = 0; nt < 2; ++nt)
#pragma unroll
            for (int j = 0; j < 4; ++j) {
                int row = mt * 16 + lgrp * 4 + j;
                int col = n0 + nt * 16 + lrow;
                as_[row * 128 + (col ^ ((row & 7) << 3))] = f2bf(fmaxf(accp[mt][nt][j], 0.f));
            }
    __syncthreads();

    // ---- GEMM_p2: (32 x 128) = a(32 x 128) @ A2(128 x 128)
    f32x4 acco[2][2];
#pragma unroll
    for (int nt = 0; nt < 2; ++nt) {
        float bv = c2[n0 + nt * 16 + lrow];
#pragma unroll
        for (int mt = 0; mt < 2; ++mt) acco[mt][nt] = (f32x4){bv, bv, bv, bv};
    }
#pragma unroll
    for (int kc = 0; kc < 4; ++kc) {
        short8 a2[2];
#pragma unroll
        for (int mt = 0; mt < 2; ++mt) {
            int r = mt * 16 + lrow;
            int kb = kc * 32 + lgrp * 8;
            a2[mt] = *(const short8*)(as_ + r * 128 + (kb ^ ((r & 7) << 3)));
        }
#pragma unroll
        for (int nt = 0; nt < 2; ++nt) {
            short8 b = *(const short8*)(A2f + ((size_t)(kc * 8 + (n0 >> 4) + nt) * 64 + lane) * 8);
#pragma unroll
            for (int mt = 0; mt < 2; ++mt)
                acco[mt][nt] = __builtin_amdgcn_mfma_f32_16x16x32_bf16(a2[mt], b, acco[mt][nt], 0, 0, 0);
        }
    }
    // epilogue: mask blend + store
#pragma unroll
    for (int mt = 0; mt < 2; ++mt)
#pragma unroll
        for (int nt = 0; nt < 2; ++nt) {
            int col = n0 + nt * 16 + lrow;
#pragma unroll
            for (int j = 0; j < 4; ++j) {
                int row = e0 + mt * 16 + lgrp * 4 + j;
                float m = A.emask[row];
                float old = oldst[(size_t)row * 128 + col];
                outst[(size_t)row * 128 + col] = m * acco[mt][nt][j] + (1.f - m) * old;
            }
        }
}

// ---------------------------------------------------------------------------
extern "C" void kernel_launch(void* const* d_in, const int* in_sizes, int n_in,
                              void* d_out, int out_size, void* d_ws, size_t ws_size,
                              hipStream_t stream) {
    const float* variable_state = (const float*)d_in[0];
    const float* function_state = (const float*)d_in[1];
    const float* dec_v          = (const float*)d_in[2];
    const float* dec_f          = (const float*)d_in[3];
    const float* ef             = (const float*)d_in[4];
    const float* meta           = (const float*)d_in[5];
    const int*   active         = (const int*)d_in[6];
    const float* vmask_t        = (const float*)d_in[8];
    const float* fmask_t        = (const float*)d_in[10];
    const float* bvm            = (const float*)d_in[11];
    const float* vM1w = (const float*)d_in[12]; const float* vM1b = (const float*)d_in[13];
    const float* vM2w = (const float*)d_in[14]; const float* vM2b = (const float*)d_in[15];
    const float* vA1w = (const float*)d_in[16]; const float* vA1b = (const float*)d_in[17];
    const float* vA2w = (const float*)d_in[18]; const float* vA2b = (const float*)d_in[19];
    const float* fM1w = (const float*)d_in[20]; const float* fM1b = (const float*)d_in[21];
    const float* fM2w = (const float*)d_in[22]; const float* fM2b = (const float*)d_in[23];
    const float* fA1w = (const float*)d_in[24]; const float* fA1b = (const float*)d_in[25];
    const float* fA2w = (const float*)d_in[26]; const float* fA2b = (const float*)d_in[27];

    float* out_vs = (float*)d_out;
    float* out_fs = (float*)d_out + (size_t)E_N * H_N;

    // workspace carve-up
    int*   var_idx = (int*)d_ws;                        // E
    int*   fun_idx = var_idx + E_N;                     // E
    int*   bov     = fun_idx + E_N;                     // V
    float* emask   = (float*)(bov + V_N);               // E
    float* gfeat   = emask + E_N;                       // 4E
    float* hv2     = gfeat + (size_t)E_N * 4;           // 128E
    float* hf2     = hv2 + (size_t)E_N * MEMAGG;        // 128E
    float* nsv     = hf2 + (size_t)E_N * MEMAGG;        // 128V
    float* nsf     = nsv + (size_t)V_N * MEMAGG;        // 128F
    unsigned short* wpack = (unsigned short*)(nsf + (size_t)F_N * MEMAGG);
    // per-branch pack: W1f 160*256 | W2f 256*128 | A1f 160*128 | A2f 128*128
    const int PBR = 160 * 256 + 256 * 128 + 160 * 128 + 128 * 128;  // 110592
    unsigned short* wpv = wpack;
    unsigned short* wpf = wpack + PBR;

    hipMemsetAsync(nsv, 0, (size_t)(V_N + F_N) * MEMAGG * sizeof(float), stream);

    RPack rp;
    rp.d[0] = {vM1w, wpv,                          IN_DIM, MEMH,   160};
    rp.d[1] = {vM2w, wpv + 160 * 256,              MEMH,   MEMAGG, 256};
    rp.d[2] = {vA1w, wpv + 160 * 256 + 256 * 128,  130,    AGGH,   160};
    rp.d[3] = {vA2w, wpv + 160 * 256 + 256 * 128 + 160 * 128, 128, H_N, 128};
    rp.d[4] = {fM1w, wpf,                          IN_DIM, MEMH,   160};
    rp.d[5] = {fM2w, wpf + 160 * 256,              MEMH,   MEMAGG, 256};
    rp.d[6] = {fA1w, wpf + 160 * 256 + 256 * 128,  130,    AGGH,   160};
    rp.d[7] = {fA2w, wpf + 160 * 256 + 256 * 128 + 160 * 128, 128, H_N, 128};
    k_repack<<<dim3(160, 8), 256, 0, stream>>>(rp);

    k_bov<<<(V_N + 255) / 256, 256, 0, stream>>>(bvm, bov);
    k_idx<<<(2 * E_N) / 4, 256, 0, stream>>>(vmask_t, fmask_t, var_idx, fun_idx);
    k_meta<<<E_N / 256, 256, 0, stream>>>(var_idx, bov, active, meta, emask, gfeat);

    F1Args f1;
    f1.dec[0] = dec_v;  f1.dec[1] = dec_f;
    f1.ef = ef;         f1.gfeat = gfeat;
    f1.wpack[0] = wpv;  f1.wpack[1] = wpf;
    f1.b1[0] = vM1b;    f1.b1[1] = fM1b;
    f1.b2[0] = vM2b;    f1.b2[1] = fM2b;
    f1.idx[0] = var_idx; f1.idx[1] = fun_idx;
    f1.h2[0] = hv2;     f1.h2[1] = hf2;
    f1.ns[0] = nsv;     f1.ns[1] = nsf;
    k_fused1<<<dim3(E_N / 32, 2), 256, 0, stream>>>(f1);

    F2Args f2;
    f2.wpack[0] = wpv;  f2.wpack[1] = wpf;
    f2.c1[0] = vA1b;    f2.c1[1] = fA1b;
    f2.c2[0] = vA2b;    f2.c2[1] = fA2b;
    f2.h2[0] = hv2;     f2.h2[1] = hf2;
    f2.ns[0] = nsv;     f2.ns[1] = nsf;
    f2.idx[0] = var_idx; f2.idx[1] = fun_idx;
    f2.ef = ef;         f2.emask = emask;
    f2.oldst[0] = function_state;  f2.oldst[1] = variable_state;
    f2.outst[0] = out_fs;          f2.outst[1] = out_vs;
    k_fused2<<<dim3(E_N / 32, 2), 256, 0, stream>>>(f2);
}

// Round 3
// 64.410 us; speedup vs baseline: 2.5884x; 1.0662x over previous
//
#include <hip/hip_runtime.h>

#define E_N 8192
#define V_N 2048
#define F_N 2048
#define B_N 8
#define H_N 128
#define DEC_N 128
#define EDGE_N 2
#define META_N 4
#define IN_DIM 134
#define MEMH 256
#define MEMAGG 128
#define AGGH 128

typedef __attribute__((ext_vector_type(8))) short short8;
typedef __attribute__((ext_vector_type(4))) float f32x4;

__device__ inline unsigned short f2bf(float x) {
    unsigned u = __float_as_uint(x);
    unsigned r = (u + 0x7FFFu + ((u >> 16) & 1u)) >> 16;
    return (unsigned short)r;
}

__device__ inline short8 pack8(float4 u0, float4 u1) {
    short8 s;
    s[0] = (short)f2bf(u0.x); s[1] = (short)f2bf(u0.y);
    s[2] = (short)f2bf(u0.z); s[3] = (short)f2bf(u0.w);
    s[4] = (short)f2bf(u1.x); s[5] = (short)f2bf(u1.y);
    s[6] = (short)f2bf(u1.z); s[7] = (short)f2bf(u1.w);
    return s;
}

// ---------------------------------------------------------------------------
__global__ void k_bov(const float* __restrict__ bvm, int* __restrict__ bov) {
    int v = blockIdx.x * blockDim.x + threadIdx.x;
    if (v < V_N) {
        float s = 0.f;
#pragma unroll
        for (int b = 0; b < B_N; ++b) s += bvm[v * B_N + b] * (float)b;
        bov[v] = (int)(s + 0.5f);
    }
}

// ---------------------------------------------------------------------------
// One wave per row of the transposed incidence matrix; early-exit scan for
// the single 1 in each one-hot row. Variable-branch waves also emit the
// per-edge mask and graph features (fused former k_meta).
__global__ __launch_bounds__(256) void k_idx(const float* __restrict__ vmt,
                                             const float* __restrict__ fmt,
                                             int* __restrict__ vidx,
                                             int* __restrict__ fidx,
                                             const int* __restrict__ bov,
                                             const int* __restrict__ active,
                                             const float* __restrict__ meta,
                                             float* __restrict__ emask,
                                             float* __restrict__ gfeat) {
    int wave = (int)((blockIdx.x * blockDim.x + threadIdx.x) >> 6);
    int lane = threadIdx.x & 63;
    const float* m;
    int* out;
    int e;
    bool isVar = wave < E_N;
    if (isVar) { m = vmt; out = vidx; e = wave; }
    else       { m = fmt; out = fidx; e = wave - E_N; }
    const float4* row = (const float4*)(m + (size_t)e * V_N);
    for (int base = 0; base < V_N / 4; base += 64) {
        float4 v = row[base + lane];
        int hit = -1;
        int c = (base + lane) * 4;
        if      (v.x != 0.f) hit = c;
        else if (v.y != 0.f) hit = c + 1;
        else if (v.z != 0.f) hit = c + 2;
        else if (v.w != 0.f) hit = c + 3;
        unsigned long long bm = __ballot(hit >= 0);
        if (bm) {
            int src = __ffsll((long long)bm) - 1;
            int val = __shfl(hit, src);
            if (lane == 0) {
                out[e] = val;
                if (isVar) {
                    int b = bov[val];
                    emask[e] = (float)active[b];
                    ((float4*)gfeat)[e] = ((const float4*)meta)[b];
                }
            }
            break;
        }
    }
}

// ---------------------------------------------------------------------------
// Repack fp32 weights into MFMA B-fragment order, bf16, K padded to Kp with 0.
// Also zeroes the node-sum buffers (replaces the pathological rocclr fill).
struct RDesc { const float* src; unsigned short* dst; int K; int N; int Kp; };
struct RPack { RDesc d[8]; float* nszero; };

__global__ __launch_bounds__(256) void k_repack(RPack p) {
    // side job: zero (V_N+F_N)*MEMAGG floats of node sums, float4 per thread
    int gid = (int)((blockIdx.y * gridDim.x + blockIdx.x) * 256 + threadIdx.x);
    const int NZ4 = (V_N + F_N) * MEMAGG / 4;  // 131072
    if (gid < NZ4) ((float4*)p.nszero)[gid] = (float4){0.f, 0.f, 0.f, 0.f};

    RDesc d = p.d[blockIdx.y];
    int i = blockIdx.x * 256 + threadIdx.x;
    int total = d.Kp * d.N;
    if (i >= total) return;
    int elem = i & 7;
    int lane = (i >> 3) & 63;
    int f    = i >> 9;
    int c16n = d.N >> 4;
    int c16 = f % c16n, kc = f / c16n;
    int k = kc * 32 + (lane >> 4) * 8 + elem;
    int c = c16 * 16 + (lane & 15);
    float v = (k < d.K) ? d.src[(size_t)k * d.N + c] : 0.f;
    d.dst[i] = f2bf(v);
}

// ---------------------------------------------------------------------------
// Fused MLP1+MLP2 per edge via MFMA: h1 = relu(dvs@W1+b1); h2 = h1@W2+b2;
// h2 -> global + atomic scatter into per-node sums. Block = 32 edges, 4 waves.
struct F1Args {
    const float* dec[2];
    const float* ef;
    const float* gfeat;
    const unsigned short* wpack[2];
    const float* b1[2];
    const float* b2[2];
    const int* idx[2];
    float* h2[2];
    float* ns[2];
};

__global__ __launch_bounds__(256) void k_fused1(F1Args A) {
    int br = blockIdx.y;
    const float* dec = A.dec[br];
    const unsigned short* W1f = A.wpack[br];
    const unsigned short* W2f = A.wpack[br] + 160 * 256;
    const float* b1 = A.b1[br];
    const float* b2 = A.b2[br];
    const int* idx = A.idx[br];
    float* h2o = A.h2[br];
    float* ns  = A.ns[br];

    int tid = threadIdx.x;
    int wave = tid >> 6, lane = tid & 63;
    int lrow = lane & 15, lgrp = lane >> 4;
    int e0 = blockIdx.x * 32;

    __shared__ unsigned short h1s[32 * 256];

    // ---- GEMM1: (32 x 256) = dvs(32 x 160pad) @ W1(160 x 256); wave owns 64 cols
    int n0 = wave * 64;
    f32x4 acc1[2][4];
#pragma unroll
    for (int nt = 0; nt < 4; ++nt) {
        float bv = b1[n0 + nt * 16 + lrow];
#pragma unroll
        for (int mt = 0; mt < 2; ++mt) acc1[mt][nt] = (f32x4){bv, bv, bv, bv};
    }
    const float4* dec4 = (const float4*)dec;
#pragma unroll
    for (int kc = 0; kc < 5; ++kc) {
        short8 a[2];
#pragma unroll
        for (int mt = 0; mt < 2; ++mt) {
            int r = e0 + mt * 16 + lrow;
            if (kc < 4) {
                float4 u0 = dec4[(size_t)r * 32 + kc * 8 + lgrp * 2];
                float4 u1 = dec4[(size_t)r * 32 + kc * 8 + lgrp * 2 + 1];
                a[mt] = pack8(u0, u1);
            } else {
                short8 z = (short8)0;
                if (lgrp == 0) {
                    z[0] = (short)f2bf(A.ef[r * 2]);
                    z[1] = (short)f2bf(A.ef[r * 2 + 1]);
                    z[2] = (short)f2bf(A.gfeat[r * 4]);
                    z[3] = (short)f2bf(A.gfeat[r * 4 + 1]);
                    z[4] = (short)f2bf(A.gfeat[r * 4 + 2]);
                    z[5] = (short)f2bf(A.gfeat[r * 4 + 3]);
                }
                a[mt] = z;
            }
        }
#pragma unroll
        for (int nt = 0; nt < 4; ++nt) {
            short8 b = *(const short8*)(W1f + ((size_t)(kc * 16 + (n0 >> 4) + nt) * 64 + lane) * 8);
#pragma unroll
            for (int mt = 0; mt < 2; ++mt)
                acc1[mt][nt] = __builtin_amdgcn_mfma_f32_16x16x32_bf16(a[mt], b, acc1[mt][nt], 0, 0, 0);
        }
    }
    // relu -> LDS (bf16, XOR-swizzled cols to kill bank conflicts)
#pragma unroll
    for (int mt = 0; mt < 2; ++mt)
#pragma unroll
        for (int nt = 0; nt < 4; ++nt)
#pragma unroll
            for (int j = 0; j < 4; ++j) {
                int row = mt * 16 + lgrp * 4 + j;
                int col = n0 + nt * 16 + lrow;
                h1s[row * 256 + (col ^ ((row & 7) << 3))] = f2bf(fmaxf(acc1[mt][nt][j], 0.f));
            }
    __syncthreads();

    // ---- GEMM2: (32 x 128) = h1(32 x 256) @ W2(256 x 128); wave owns 32 cols
    int c0 = wave * 32;
    f32x4 acc2[2][2];
#pragma unroll
    for (int nt = 0; nt < 2; ++nt) {
        float bv = b2[c0 + nt * 16 + lrow];
#pragma unroll
        for (int mt = 0; mt < 2; ++mt) acc2[mt][nt] = (f32x4){bv, bv, bv, bv};
    }
#pragma unroll
    for (int kc = 0; kc < 8; ++kc) {
        short8 a2[2];
#pragma unroll
        for (int mt = 0; mt < 2; ++mt) {
            int r = mt * 16 + lrow;
            int kb = kc * 32 + lgrp * 8;
            a2[mt] = *(const short8*)(h1s + r * 256 + (kb ^ ((r & 7) << 3)));
        }
#pragma unroll
        for (int nt = 0; nt < 2; ++nt) {
            short8 b = *(const short8*)(W2f + ((size_t)(kc * 8 + (c0 >> 4) + nt) * 64 + lane) * 8);
#pragma unroll
            for (int mt = 0; mt < 2; ++mt)
                acc2[mt][nt] = __builtin_amdgcn_mfma_f32_16x16x32_bf16(a2[mt], b, acc2[mt][nt], 0, 0, 0);
        }
    }
    // h2 -> global; scatter-add into node sums
#pragma unroll
    for (int mt = 0; mt < 2; ++mt)
#pragma unroll
        for (int nt = 0; nt < 2; ++nt) {
            int col = c0 + nt * 16 + lrow;
#pragma unroll
            for (int j = 0; j < 4; ++j) {
                int row = e0 + mt * 16 + lgrp * 4 + j;
                float v = acc2[mt][nt][j];
                h2o[(size_t)row * 128 + col] = v;
                atomicAdd(ns + (size_t)idx[row] * 128 + col, v);
            }
        }
}

// ---------------------------------------------------------------------------
// Fused post: agg = ns[idx]-h2; a = relu([agg,ef]@A1+c1); o = a@A2+c2;
// out = m*o + (1-m)*old.
struct F2Args {
    const unsigned short* wpack[2];
    const float* c1[2];
    const float* c2[2];
    const float* h2[2];
    const float* ns[2];
    const int* idx[2];
    const float* ef;
    const float* emask;
    const float* oldst[2];
    float* outst[2];
};

__global__ __launch_bounds__(256) void k_fused2(F2Args A) {
    int br = blockIdx.y;
    const unsigned short* A1f = A.wpack[br] + 160 * 256 + 256 * 128;
    const unsigned short* A2f = A1f + 160 * 128;
    const float* c1 = A.c1[br];
    const float* c2 = A.c2[br];
    const float* h2 = A.h2[br];
    const float* ns = A.ns[br];
    const int* idx = A.idx[br];
    const float* oldst = A.oldst[br];
    float* outst = A.outst[br];

    int tid = threadIdx.x;
    int wave = tid >> 6, lane = tid & 63;
    int lrow = lane & 15, lgrp = lane >> 4;
    int e0 = blockIdx.x * 32;

    __shared__ unsigned short as_[32 * 128];

    // ---- GEMM_p1: (32 x 128) = [agg|ef](32 x 160pad) @ A1(160 x 128)
    int n0 = wave * 32;
    f32x4 accp[2][2];
#pragma unroll
    for (int nt = 0; nt < 2; ++nt) {
        float bv = c1[n0 + nt * 16 + lrow];
#pragma unroll
        for (int mt = 0; mt < 2; ++mt) accp[mt][nt] = (f32x4){bv, bv, bv, bv};
    }
    const float4* ns4 = (const float4*)ns;
    const float4* h24 = (const float4*)h2;
#pragma unroll
    for (int kc = 0; kc < 5; ++kc) {
        short8 a[2];
#pragma unroll
        for (int mt = 0; mt < 2; ++mt) {
            int r = e0 + mt * 16 + lrow;
            if (kc < 4) {
                int node = idx[r];
                float4 u0 = ns4[(size_t)node * 32 + kc * 8 + lgrp * 2];
                float4 u1 = ns4[(size_t)node * 32 + kc * 8 + lgrp * 2 + 1];
                float4 v0 = h24[(size_t)r * 32 + kc * 8 + lgrp * 2];
                float4 v1 = h24[(size_t)r * 32 + kc * 8 + lgrp * 2 + 1];
                float4 d0 = {u0.x - v0.x, u0.y - v0.y, u0.z - v0.z, u0.w - v0.w};
                float4 d1 = {u1.x - v1.x, u1.y - v1.y, u1.z - v1.z, u1.w - v1.w};
                a[mt] = pack8(d0, d1);
            } else {
                short8 z = (short8)0;
                if (lgrp == 0) {
                    z[0] = (short)f2bf(A.ef[r * 2]);
                    z[1] = (short)f2bf(A.ef[r * 2 + 1]);
                }
                a[mt] = z;
            }
        }
#pragma unroll
        for (int nt = 0; nt < 2; ++nt) {
            short8 b = *(const short8*)(A1f + ((size_t)(kc * 8 + (n0 >> 4) + nt) * 64 + lane) * 8);
#pragma unroll
            for (int mt = 0; mt < 2; ++mt)
                accp[mt][nt] = __builtin_amdgcn_mfma_f32_16x16x32_bf16(a[mt], b, accp[mt][nt], 0, 0, 0);
        }
    }
    // relu -> LDS
#pragma unroll
    for (int mt = 0; mt < 2; ++mt)
#pragma unroll
        for (int nt = 0; nt < 2; ++nt)
#pragma unroll
            for (int j = 0; j < 4; ++j) {
                int row = mt * 16 + lgrp * 4 + j;
                int col = n0 + nt * 16 + lrow;
                as_[row * 128 + (col ^ ((row & 7) << 3))] = f2bf(fmaxf(accp[mt][nt][j], 0.f));
            }
    __syncthreads();

    // ---- GEMM_p2: (32 x 128) = a(32 x 128) @ A2(128 x 128)
    f32x4 acco[2][2];
#pragma unroll
    for (int nt = 0; nt < 2; ++nt) {
        float bv = c2[n0 + nt * 16 + lrow];
#pragma unroll
        for (int mt = 0; mt < 2; ++mt) acco[mt][nt] = (f32x4){bv, bv, bv, bv};
    }
#pragma unroll
    for (int kc = 0; kc < 4; ++kc) {
        short8 a2[2];
#pragma unroll
        for (int mt = 0; mt < 2; ++mt) {
            int r = mt * 16 + lrow;
            int kb = kc * 32 + lgrp * 8;
            a2[mt] = *(const short8*)(as_ + r * 128 + (kb ^ ((r & 7) << 3)));
        }
#pragma unroll
        for (int nt = 0; nt < 2; ++nt) {
            short8 b = *(const short8*)(A2f + ((size_t)(kc * 8 + (n0 >> 4) + nt) * 64 + lane) * 8);
#pragma unroll
            for (int mt = 0; mt < 2; ++mt)
                acco[mt][nt] = __builtin_amdgcn_mfma_f32_16x16x32_bf16(a2[mt], b, acco[mt][nt], 0, 0, 0);
        }
    }
    // epilogue: mask blend + store
#pragma unroll
    for (int mt = 0; mt < 2; ++mt)
#pragma unroll
        for (int nt = 0; nt < 2; ++nt) {
            int col = n0 + nt * 16 + lrow;
#pragma unroll
            for (int j = 0; j < 4; ++j) {
                int row = e0 + mt * 16 + lgrp * 4 + j;
                float m = A.emask[row];
                float old = oldst[(size_t)row * 128 + col];
                outst[(size_t)row * 128 + col] = m * acco[mt][nt][j] + (1.f - m) * old;
            }
        }
}

// ---------------------------------------------------------------------------
extern "C" void kernel_launch(void* const* d_in, const int* in_sizes, int n_in,
                              void* d_out, int out_size, void* d_ws, size_t ws_size,
                              hipStream_t stream) {
    const float* variable_state = (const float*)d_in[0];
    const float* function_state = (const float*)d_in[1];
    const float* dec_v          = (const float*)d_in[2];
    const float* dec_f          = (const float*)d_in[3];
    const float* ef             = (const float*)d_in[4];
    const float* meta           = (const float*)d_in[5];
    const int*   active         = (const int*)d_in[6];
    const float* vmask_t        = (const float*)d_in[8];
    const float* fmask_t        = (const float*)d_in[10];
    const float* bvm            = (const float*)d_in[11];
    const float* vM1w = (const float*)d_in[12]; const float* vM1b = (const float*)d_in[13];
    const float* vM2w = (const float*)d_in[14]; const float* vM2b = (const float*)d_in[15];
    const float* vA1w = (const float*)d_in[16]; const float* vA1b = (const float*)d_in[17];
    const float* vA2w = (const float*)d_in[18]; const float* vA2b = (const float*)d_in[19];
    const float* fM1w = (const float*)d_in[20]; const float* fM1b = (const float*)d_in[21];
    const float* fM2w = (const float*)d_in[22]; const float* fM2b = (const float*)d_in[23];
    const float* fA1w = (const float*)d_in[24]; const float* fA1b = (const float*)d_in[25];
    const float* fA2w = (const float*)d_in[26]; const float* fA2b = (const float*)d_in[27];

    float* out_vs = (float*)d_out;
    float* out_fs = (float*)d_out + (size_t)E_N * H_N;

    // workspace carve-up
    int*   var_idx = (int*)d_ws;                        // E
    int*   fun_idx = var_idx + E_N;                     // E
    int*   bov     = fun_idx + E_N;                     // V
    float* emask   = (float*)(bov + V_N);               // E
    float* gfeat   = emask + E_N;                       // 4E
    float* hv2     = gfeat + (size_t)E_N * 4;           // 128E
    float* hf2     = hv2 + (size_t)E_N * MEMAGG;        // 128E
    float* nsv     = hf2 + (size_t)E_N * MEMAGG;        // 128V
    float* nsf     = nsv + (size_t)V_N * MEMAGG;        // 128F
    unsigned short* wpack = (unsigned short*)(nsf + (size_t)F_N * MEMAGG);
    const int PBR = 160 * 256 + 256 * 128 + 160 * 128 + 128 * 128;  // 110592
    unsigned short* wpv = wpack;
    unsigned short* wpf = wpack + PBR;

    RPack rp;
    rp.d[0] = {vM1w, wpv,                          IN_DIM, MEMH,   160};
    rp.d[1] = {vM2w, wpv + 160 * 256,              MEMH,   MEMAGG, 256};
    rp.d[2] = {vA1w, wpv + 160 * 256 + 256 * 128,  130,    AGGH,   160};
    rp.d[3] = {vA2w, wpv + 160 * 256 + 256 * 128 + 160 * 128, 128, H_N, 128};
    rp.d[4] = {fM1w, wpf,                          IN_DIM, MEMH,   160};
    rp.d[5] = {fM2w, wpf + 160 * 256,              MEMH,   MEMAGG, 256};
    rp.d[6] = {fA1w, wpf + 160 * 256 + 256 * 128,  130,    AGGH,   160};
    rp.d[7] = {fA2w, wpf + 160 * 256 + 256 * 128 + 160 * 128, 128, H_N, 128};
    rp.nszero = nsv;  // zeroes nsv and nsf ((V+F)*128 contiguous floats)
    k_repack<<<dim3(160, 8), 256, 0, stream>>>(rp);

    k_bov<<<(V_N + 255) / 256, 256, 0, stream>>>(bvm, bov);
    k_idx<<<(2 * E_N) / 4, 256, 0, stream>>>(vmask_t, fmask_t, var_idx, fun_idx,
                                             bov, active, meta, emask, gfeat);

    F1Args f1;
    f1.dec[0] = dec_v;  f1.dec[1] = dec_f;
    f1.ef = ef;         f1.gfeat = gfeat;
    f1.wpack[0] = wpv;  f1.wpack[1] = wpf;
    f1.b1[0] = vM1b;    f1.b1[1] = fM1b;
    f1.b2[0] = vM2b;    f1.b2[1] = fM2b;
    f1.idx[0] = var_idx; f1.idx[1] = fun_idx;
    f1.h2[0] = hv2;     f1.h2[1] = hf2;
    f1.ns[0] = nsv;     f1.ns[1] = nsf;
    k_fused1<<<dim3(E_N / 32, 2), 256, 0, stream>>>(f1);

    F2Args f2;
    f2.wpack[0] = wpv;  f2.wpack[1] = wpf;
    f2.c1[0] = vA1b;    f2.c1[1] = fA1b;
    f2.c2[0] = vA2b;    f2.c2[1] = fA2b;
    f2.h2[0] = hv2;     f2.h2[1] = hf2;
    f2.ns[0] = nsv;     f2.ns[1] = nsf;
    f2.idx[0] = var_idx; f2.idx[1] = fun_idx;
    f2.ef = ef;         f2.emask = emask;
    f2.oldst[0] = function_state;  f2.oldst[1] = variable_state;
    f2.outst[0] = out_fs;          f2.outst[1] = out_vs;
    k_fused2<<<dim3(E_N / 32, 2), 256, 0, stream>>>(f2);
}

// Round 4
// 58.375 us; speedup vs baseline: 2.8560x; 1.1034x over previous
//
#include <hip/hip_runtime.h>

#define E_N 8192
#define V_N 2048
#define F_N 2048
#define B_N 8
#define H_N 128
#define DEC_N 128
#define EDGE_N 2
#define META_N 4
#define IN_DIM 134
#define MEMH 256
#define MEMAGG 128
#define AGGH 128

typedef __attribute__((ext_vector_type(8))) short short8;
typedef __attribute__((ext_vector_type(4))) float f32x4;

__device__ inline unsigned short f2bf(float x) {
    unsigned u = __float_as_uint(x);
    unsigned r = (u + 0x7FFFu + ((u >> 16) & 1u)) >> 16;
    return (unsigned short)r;
}

__device__ inline short8 pack8(float4 u0, float4 u1) {
    short8 s;
    s[0] = (short)f2bf(u0.x); s[1] = (short)f2bf(u0.y);
    s[2] = (short)f2bf(u0.z); s[3] = (short)f2bf(u0.w);
    s[4] = (short)f2bf(u1.x); s[5] = (short)f2bf(u1.y);
    s[6] = (short)f2bf(u1.z); s[7] = (short)f2bf(u1.w);
    return s;
}

// ---------------------------------------------------------------------------
// Setup: repack fp32 weights into MFMA B-fragment order (bf16, K zero-padded
// to Kp), zero the node-sum buffers, compute batch_of_var. One launch.
struct RDesc { const float* src; unsigned short* dst; int K; int N; int Kp; };
struct SetupArgs { RDesc d[8]; float* nszero; const float* bvm; int* bov; };

__global__ __launch_bounds__(256) void k_setup(SetupArgs p) {
    if (blockIdx.y == 8) {          // bov lane: 8 blocks cover V_N=2048
        if (blockIdx.x < 8) {
            int v = blockIdx.x * 256 + threadIdx.x;
            float s = 0.f;
#pragma unroll
            for (int b = 0; b < B_N; ++b) s += p.bvm[v * B_N + b] * (float)b;
            p.bov[v] = (int)(s + 0.5f);
        }
        return;
    }
    // zero node sums: (V+F)*128 floats = 131072 float4, grid covers 327680
    int gid = (int)((blockIdx.y * 160 + blockIdx.x) * 256 + threadIdx.x);
    const int NZ4 = (V_N + F_N) * MEMAGG / 4;
    if (gid < NZ4) ((float4*)p.nszero)[gid] = (float4){0.f, 0.f, 0.f, 0.f};

    RDesc d = p.d[blockIdx.y];
    int i = blockIdx.x * 256 + threadIdx.x;
    int total = d.Kp * d.N;
    if (i >= total) return;
    int elem = i & 7;
    int lane = (i >> 3) & 63;
    int f    = i >> 9;
    int c16n = d.N >> 4;
    int c16 = f % c16n, kc = f / c16n;
    int k = kc * 32 + (lane >> 4) * 8 + elem;
    int c = c16 * 16 + (lane & 15);
    float v = (k < d.K) ? d.src[(size_t)k * d.N + c] : 0.f;
    d.dst[i] = f2bf(v);
}

// ---------------------------------------------------------------------------
// One wave per row of the transposed incidence matrices. Batch-4 independent
// float4 loads (1024 floats per check) so the dependent chain is <=2 HBM
// round-trips instead of <=8. Variable-branch waves also emit emask/gfeat.
__global__ __launch_bounds__(256) void k_idx(const float* __restrict__ vmt,
                                             const float* __restrict__ fmt,
                                             int* __restrict__ vidx,
                                             int* __restrict__ fidx,
                                             const int* __restrict__ bov,
                                             const int* __restrict__ active,
                                             const float* __restrict__ meta,
                                             float* __restrict__ emask,
                                             float* __restrict__ gfeat) {
    int wave = (int)((blockIdx.x * blockDim.x + threadIdx.x) >> 6);
    int lane = threadIdx.x & 63;
    bool isVar = wave < E_N;
    const float* m = isVar ? vmt : fmt;
    int* out = isVar ? vidx : fidx;
    int e = isVar ? wave : wave - E_N;
    const float4* row = (const float4*)(m + (size_t)e * V_N);

    int pos = -1;
#pragma unroll
    for (int half = 0; half < 2; ++half) {
        if (pos < 0) {                       // wave-uniform (pos from shfl)
            float4 v0 = row[half * 256 + lane];
            float4 v1 = row[half * 256 + 64 + lane];
            float4 v2 = row[half * 256 + 128 + lane];
            float4 v3 = row[half * 256 + 192 + lane];
            int hit = -1;
            float4 vv[4] = {v0, v1, v2, v3};
#pragma unroll
            for (int j = 0; j < 4; ++j) {
                float4 v = vv[j];
                int c = (half * 256 + j * 64 + lane) * 4;
                if (hit < 0) {
                    if      (v.x != 0.f) hit = c;
                    else if (v.y != 0.f) hit = c + 1;
                    else if (v.z != 0.f) hit = c + 2;
                    else if (v.w != 0.f) hit = c + 3;
                }
            }
            unsigned long long bm = __ballot(hit >= 0);
            if (bm) pos = __shfl(hit, __ffsll((long long)bm) - 1);
        }
    }
    if (lane == 0) {
        out[e] = pos;
        if (isVar) {
            int b = bov[pos];
            emask[e] = (float)active[b];
            ((float4*)gfeat)[e] = ((const float4*)meta)[b];
        }
    }
}

// ---------------------------------------------------------------------------
// Fused MLP1+MLP2 per edge via MFMA, 16 edges/block (4 waves), grid 512x2.
struct F1Args {
    const float* dec[2];
    const float* ef;
    const float* gfeat;
    const unsigned short* wpack[2];
    const float* b1[2];
    const float* b2[2];
    const int* idx[2];
    float* h2[2];
    float* ns[2];
};

__global__ __launch_bounds__(256) void k_fused1(F1Args A) {
    int br = blockIdx.y;
    const float* dec = A.dec[br];
    const unsigned short* W1f = A.wpack[br];
    const unsigned short* W2f = A.wpack[br] + 160 * 256;
    const float* b1 = A.b1[br];
    const float* b2 = A.b2[br];
    const int* idx = A.idx[br];
    float* h2o = A.h2[br];
    float* ns  = A.ns[br];

    int tid = threadIdx.x;
    int wave = tid >> 6, lane = tid & 63;
    int lrow = lane & 15, lgrp = lane >> 4;
    int e0 = blockIdx.x * 16;

    __shared__ unsigned short h1s[16 * 256];  // 8 KB

    // ---- GEMM1: (16 x 256) = dvs(16 x 160pad) @ W1; wave owns 64 cols
    int n0 = wave * 64;
    f32x4 acc1[4];
#pragma unroll
    for (int nt = 0; nt < 4; ++nt) {
        float bv = b1[n0 + nt * 16 + lrow];
        acc1[nt] = (f32x4){bv, bv, bv, bv};
    }
    const float4* dec4 = (const float4*)dec;
    int r = e0 + lrow;
#pragma unroll
    for (int kc = 0; kc < 5; ++kc) {
        short8 a;
        if (kc < 4) {
            float4 u0 = dec4[(size_t)r * 32 + kc * 8 + lgrp * 2];
            float4 u1 = dec4[(size_t)r * 32 + kc * 8 + lgrp * 2 + 1];
            a = pack8(u0, u1);
        } else {
            short8 z = (short8)0;
            if (lgrp == 0) {
                z[0] = (short)f2bf(A.ef[r * 2]);
                z[1] = (short)f2bf(A.ef[r * 2 + 1]);
                z[2] = (short)f2bf(A.gfeat[r * 4]);
                z[3] = (short)f2bf(A.gfeat[r * 4 + 1]);
                z[4] = (short)f2bf(A.gfeat[r * 4 + 2]);
                z[5] = (short)f2bf(A.gfeat[r * 4 + 3]);
            }
            a = z;
        }
#pragma unroll
        for (int nt = 0; nt < 4; ++nt) {
            short8 b = *(const short8*)(W1f + ((size_t)(kc * 16 + (n0 >> 4) + nt) * 64 + lane) * 8);
            acc1[nt] = __builtin_amdgcn_mfma_f32_16x16x32_bf16(a, b, acc1[nt], 0, 0, 0);
        }
    }
    // relu -> LDS (bf16, XOR-swizzled)
#pragma unroll
    for (int nt = 0; nt < 4; ++nt)
#pragma unroll
        for (int j = 0; j < 4; ++j) {
            int row = lgrp * 4 + j;
            int col = n0 + nt * 16 + lrow;
            h1s[row * 256 + (col ^ ((row & 7) << 3))] = f2bf(fmaxf(acc1[nt][j], 0.f));
        }
    __syncthreads();

    // ---- GEMM2: (16 x 128) = h1 @ W2; wave owns 32 cols
    int c0 = wave * 32;
    f32x4 acc2[2];
#pragma unroll
    for (int nt = 0; nt < 2; ++nt) {
        float bv = b2[c0 + nt * 16 + lrow];
        acc2[nt] = (f32x4){bv, bv, bv, bv};
    }
#pragma unroll
    for (int kc = 0; kc < 8; ++kc) {
        int kb = kc * 32 + lgrp * 8;
        short8 a2 = *(const short8*)(h1s + lrow * 256 + (kb ^ ((lrow & 7) << 3)));
#pragma unroll
        for (int nt = 0; nt < 2; ++nt) {
            short8 b = *(const short8*)(W2f + ((size_t)(kc * 8 + (c0 >> 4) + nt) * 64 + lane) * 8);
            acc2[nt] = __builtin_amdgcn_mfma_f32_16x16x32_bf16(a2, b, acc2[nt], 0, 0, 0);
        }
    }
    // h2 -> global; scatter-add into node sums
#pragma unroll
    for (int j = 0; j < 4; ++j) {
        int row = e0 + lgrp * 4 + j;
        int node = idx[row];
#pragma unroll
        for (int nt = 0; nt < 2; ++nt) {
            int col = c0 + nt * 16 + lrow;
            float v = acc2[nt][j];
            h2o[(size_t)row * 128 + col] = v;
            atomicAdd(ns + (size_t)node * 128 + col, v);
        }
    }
}

// ---------------------------------------------------------------------------
// Fused post, 16 edges/block: agg = ns[idx]-h2; a = relu([agg,ef]@A1+c1);
// o = a@A2+c2; out = m*o + (1-m)*old.
struct F2Args {
    const unsigned short* wpack[2];
    const float* c1[2];
    const float* c2[2];
    const float* h2[2];
    const float* ns[2];
    const int* idx[2];
    const float* ef;
    const float* emask;
    const float* oldst[2];
    float* outst[2];
};

__global__ __launch_bounds__(256) void k_fused2(F2Args A) {
    int br = blockIdx.y;
    const unsigned short* A1f = A.wpack[br] + 160 * 256 + 256 * 128;
    const unsigned short* A2f = A1f + 160 * 128;
    const float* c1 = A.c1[br];
    const float* c2 = A.c2[br];
    const float* h2 = A.h2[br];
    const float* ns = A.ns[br];
    const int* idx = A.idx[br];
    const float* oldst = A.oldst[br];
    float* outst = A.outst[br];

    int tid = threadIdx.x;
    int wave = tid >> 6, lane = tid & 63;
    int lrow = lane & 15, lgrp = lane >> 4;
    int e0 = blockIdx.x * 16;

    __shared__ unsigned short as_[16 * 128];  // 4 KB

    // ---- GEMM_p1: (16 x 128) = [agg|ef](16 x 160pad) @ A1; wave owns 32 cols
    int n0 = wave * 32;
    f32x4 accp[2];
#pragma unroll
    for (int nt = 0; nt < 2; ++nt) {
        float bv = c1[n0 + nt * 16 + lrow];
        accp[nt] = (f32x4){bv, bv, bv, bv};
    }
    const float4* ns4 = (const float4*)ns;
    const float4* h24 = (const float4*)h2;
    int r = e0 + lrow;
    int node = idx[r];
#pragma unroll
    for (int kc = 0; kc < 5; ++kc) {
        short8 a;
        if (kc < 4) {
            float4 u0 = ns4[(size_t)node * 32 + kc * 8 + lgrp * 2];
            float4 u1 = ns4[(size_t)node * 32 + kc * 8 + lgrp * 2 + 1];
            float4 v0 = h24[(size_t)r * 32 + kc * 8 + lgrp * 2];
            float4 v1 = h24[(size_t)r * 32 + kc * 8 + lgrp * 2 + 1];
            float4 d0 = {u0.x - v0.x, u0.y - v0.y, u0.z - v0.z, u0.w - v0.w};
            float4 d1 = {u1.x - v1.x, u1.y - v1.y, u1.z - v1.z, u1.w - v1.w};
            a = pack8(d0, d1);
        } else {
            short8 z = (short8)0;
            if (lgrp == 0) {
                z[0] = (short)f2bf(A.ef[r * 2]);
                z[1] = (short)f2bf(A.ef[r * 2 + 1]);
            }
            a = z;
        }
#pragma unroll
        for (int nt = 0; nt < 2; ++nt) {
            short8 b = *(const short8*)(A1f + ((size_t)(kc * 8 + (n0 >> 4) + nt) * 64 + lane) * 8);
            accp[nt] = __builtin_amdgcn_mfma_f32_16x16x32_bf16(a, b, accp[nt], 0, 0, 0);
        }
    }
    // relu -> LDS
#pragma unroll
    for (int nt = 0; nt < 2; ++nt)
#pragma unroll
        for (int j = 0; j < 4; ++j) {
            int row = lgrp * 4 + j;
            int col = n0 + nt * 16 + lrow;
            as_[row * 128 + (col ^ ((row & 7) << 3))] = f2bf(fmaxf(accp[nt][j], 0.f));
        }
    __syncthreads();

    // ---- GEMM_p2: (16 x 128) = a @ A2
    f32x4 acco[2];
#pragma unroll
    for (int nt = 0; nt < 2; ++nt) {
        float bv = c2[n0 + nt * 16 + lrow];
        acco[nt] = (f32x4){bv, bv, bv, bv};
    }
#pragma unroll
    for (int kc = 0; kc < 4; ++kc) {
        int kb = kc * 32 + lgrp * 8;
        short8 a2 = *(const short8*)(as_ + lrow * 128 + (kb ^ ((lrow & 7) << 3)));
#pragma unroll
        for (int nt = 0; nt < 2; ++nt) {
            short8 b = *(const short8*)(A2f + ((size_t)(kc * 8 + (n0 >> 4) + nt) * 64 + lane) * 8);
            acco[nt] = __builtin_amdgcn_mfma_f32_16x16x32_bf16(a2, b, acco[nt], 0, 0, 0);
        }
    }
    // epilogue: mask blend + store
#pragma unroll
    for (int j = 0; j < 4; ++j) {
        int row = e0 + lgrp * 4 + j;
        float m = A.emask[row];
#pragma unroll
        for (int nt = 0; nt < 2; ++nt) {
            int col = n0 + nt * 16 + lrow;
            float old = oldst[(size_t)row * 128 + col];
            outst[(size_t)row * 128 + col] = m * acco[nt][j] + (1.f - m) * old;
        }
    }
}

// ---------------------------------------------------------------------------
extern "C" void kernel_launch(void* const* d_in, const int* in_sizes, int n_in,
                              void* d_out, int out_size, void* d_ws, size_t ws_size,
                              hipStream_t stream) {
    const float* variable_state = (const float*)d_in[0];
    const float* function_state = (const float*)d_in[1];
    const float* dec_v          = (const float*)d_in[2];
    const float* dec_f          = (const float*)d_in[3];
    const float* ef             = (const float*)d_in[4];
    const float* meta           = (const float*)d_in[5];
    const int*   active         = (const int*)d_in[6];
    const float* vmask_t        = (const float*)d_in[8];
    const float* fmask_t        = (const float*)d_in[10];
    const float* bvm            = (const float*)d_in[11];
    const float* vM1w = (const float*)d_in[12]; const float* vM1b = (const float*)d_in[13];
    const float* vM2w = (const float*)d_in[14]; const float* vM2b = (const float*)d_in[15];
    const float* vA1w = (const float*)d_in[16]; const float* vA1b = (const float*)d_in[17];
    const float* vA2w = (const float*)d_in[18]; const float* vA2b = (const float*)d_in[19];
    const float* fM1w = (const float*)d_in[20]; const float* fM1b = (const float*)d_in[21];
    const float* fM2w = (const float*)d_in[22]; const float* fM2b = (const float*)d_in[23];
    const float* fA1w = (const float*)d_in[24]; const float* fA1b = (const float*)d_in[25];
    const float* fA2w = (const float*)d_in[26]; const float* fA2b = (const float*)d_in[27];

    float* out_vs = (float*)d_out;
    float* out_fs = (float*)d_out + (size_t)E_N * H_N;

    // workspace carve-up
    int*   var_idx = (int*)d_ws;                        // E
    int*   fun_idx = var_idx + E_N;                     // E
    int*   bov     = fun_idx + E_N;                     // V
    float* emask   = (float*)(bov + V_N);               // E
    float* gfeat   = emask + E_N;                       // 4E
    float* hv2     = gfeat + (size_t)E_N * 4;           // 128E
    float* hf2     = hv2 + (size_t)E_N * MEMAGG;        // 128E
    float* nsv     = hf2 + (size_t)E_N * MEMAGG;        // 128V
    float* nsf     = nsv + (size_t)V_N * MEMAGG;        // 128F
    unsigned short* wpack = (unsigned short*)(nsf + (size_t)F_N * MEMAGG);
    const int PBR = 160 * 256 + 256 * 128 + 160 * 128 + 128 * 128;  // 110592
    unsigned short* wpv = wpack;
    unsigned short* wpf = wpack + PBR;

    SetupArgs sp;
    sp.d[0] = {vM1w, wpv,                          IN_DIM, MEMH,   160};
    sp.d[1] = {vM2w, wpv + 160 * 256,              MEMH,   MEMAGG, 256};
    sp.d[2] = {vA1w, wpv + 160 * 256 + 256 * 128,  130,    AGGH,   160};
    sp.d[3] = {vA2w, wpv + 160 * 256 + 256 * 128 + 160 * 128, 128, H_N, 128};
    sp.d[4] = {fM1w, wpf,                          IN_DIM, MEMH,   160};
    sp.d[5] = {fM2w, wpf + 160 * 256,              MEMH,   MEMAGG, 256};
    sp.d[6] = {fA1w, wpf + 160 * 256 + 256 * 128,  130,    AGGH,   160};
    sp.d[7] = {fA2w, wpf + 160 * 256 + 256 * 128 + 160 * 128, 128, H_N, 128};
    sp.nszero = nsv;
    sp.bvm = bvm;
    sp.bov = bov;
    k_setup<<<dim3(160, 9), 256, 0, stream>>>(sp);

    k_idx<<<(2 * E_N) / 4, 256, 0, stream>>>(vmask_t, fmask_t, var_idx, fun_idx,
                                             bov, active, meta, emask, gfeat);

    F1Args f1;
    f1.dec[0] = dec_v;  f1.dec[1] = dec_f;
    f1.ef = ef;         f1.gfeat = gfeat;
    f1.wpack[0] = wpv;  f1.wpack[1] = wpf;
    f1.b1[0] = vM1b;    f1.b1[1] = fM1b;
    f1.b2[0] = vM2b;    f1.b2[1] = fM2b;
    f1.idx[0] = var_idx; f1.idx[1] = fun_idx;
    f1.h2[0] = hv2;     f1.h2[1] = hf2;
    f1.ns[0] = nsv;     f1.ns[1] = nsf;
    k_fused1<<<dim3(E_N / 16, 2), 256, 0, stream>>>(f1);

    F2Args f2;
    f2.wpack[0] = wpv;  f2.wpack[1] = wpf;
    f2.c1[0] = vA1b;    f2.c1[1] = fA1b;
    f2.c2[0] = vA2b;    f2.c2[1] = fA2b;
    f2.h2[0] = hv2;     f2.h2[1] = hf2;
    f2.ns[0] = nsv;     f2.ns[1] = nsf;
    f2.idx[0] = var_idx; f2.idx[1] = fun_idx;
    f2.ef = ef;         f2.emask = emask;
    f2.oldst[0] = function_state;  f2.oldst[1] = variable_state;
    f2.outst[0] = out_fs;          f2.outst[1] = out_vs;
    k_fused2<<<dim3(E_N / 16, 2), 256, 0, stream>>>(f2);
}